// Round 7
// baseline (61.878 us; speedup 1.0000x reference)
//
#include <hip/hip_runtime.h>

#define NB 65536
#define NJ 24
#define NTRK 6
#define GRP 8         // lanes per batch (24/3, no idle lanes)
#define JPL 3         // joints per lane
#define BPB 32        // batches per tile (256 threads / 8 lanes)
#define TILES 2       // tiles per block, software-pipelined
#define PAD3 72       // f4 per batch in LDS: 24 joints x 3 rows

typedef float f4 __attribute__((ext_vector_type(4)));

__device__ __forceinline__ void rpy2R(float r, float p, float y, float* R) {
    float cr = cosf(r), sr = sinf(r);
    float cp = cosf(p), sp = sinf(p);
    float cy = cosf(y), sy = sinf(y);
    R[0] = cy * cp; R[1] = cy * sp * sr - sy * cr; R[2] = cy * sp * cr + sy * sr;
    R[3] = sy * cp; R[4] = sy * sp * sr + cy * cr; R[5] = sy * sp * cr - cy * sr;
    R[6] = -sp;     R[7] = cp * sr;                R[8] = cp * cr;
}

// C = A o B (SE3): Rc = Ra*Rb, pc = Ra*pb + pa.  C must not alias A or B.
__device__ __forceinline__ void compose(const float* Ra, const float* pa,
                                        const float* Rb, const float* pb,
                                        float* Rc, float* pc) {
#pragma unroll
    for (int i = 0; i < 3; i++) {
        float a0 = Ra[i*3+0], a1 = Ra[i*3+1], a2 = Ra[i*3+2];
        Rc[i*3+0] = a0*Rb[0] + a1*Rb[3] + a2*Rb[6];
        Rc[i*3+1] = a0*Rb[1] + a1*Rb[4] + a2*Rb[7];
        Rc[i*3+2] = a0*Rb[2] + a1*Rb[5] + a2*Rb[8];
        pc[i]     = a0*pb[0] + a1*pb[1] + a2*pb[2] + pa[i];
    }
}

// Full per-tile compute for one thread: serial 3-joint pass, 8-lane scan,
// tracked-frame store (direct to global), finalized JointSE3 rows in FR/Fp.
__device__ __forceinline__ void tile_compute(
    int b, int g, const float4* s_stat,
    const float* qr, const float* qp,
    float* __restrict__ out_track,
    float FR[JPL][9], float Fp[JPL][3])
{
    float preR[JPL][9], prep[JPL][3];
    float curR[9], curp[3];
    float tR[9], tp[3];
    int jt = -1;

#pragma unroll
    for (int k = 0; k < JPL; k++) {
        const int j = 3 * g + k;
        const float4 s0 = s_stat[j*8+0], s1 = s_stat[j*8+1], s2 = s_stat[j*8+2];
        const float4 s3 = s_stat[j*8+3], s4 = s_stat[j*8+4];
        float ToR[9] = {s0.x,s0.y,s0.z, s1.x,s1.y,s1.z, s2.x,s2.y,s2.z};
        float Top[3] = {s0.w, s1.w, s2.w};

        if (k == 0) {
#pragma unroll
            for (int i = 0; i < 9; i++) preR[0][i] = ToR[i];
#pragma unroll
            for (int i = 0; i < 3; i++) prep[0][i] = Top[i];
        } else {
            compose(curR, curp, ToR, Top, preR[k], prep[k]);
        }

        float s = __sinf(qr[k]), c = __cosf(qr[k]), c1 = 1.0f - c;
        const float ax = s3.x, ay = s3.y, az = s3.z, adot = s3.w;
        float jR[9];
        jR[0] = 1.f + c1*(ax*ax - adot);  jR[1] = -s*az + c1*ax*ay;        jR[2] =  s*ay + c1*ax*az;
        jR[3] =  s*az + c1*ax*ay;         jR[4] = 1.f + c1*(ay*ay - adot); jR[5] = -s*ax + c1*ay*az;
        jR[6] = -s*ay + c1*ax*az;         jR[7] =  s*ax + c1*ay*az;        jR[8] = 1.f + c1*(az*az - adot);
        float v0 = qp[k]*s4.x, v1 = qp[k]*s4.y, v2 = qp[k]*s4.z;
        float jp[3];
        jp[0] = jR[0]*v0 + jR[1]*v1 + jR[2]*v2;
        jp[1] = jR[3]*v0 + jR[4]*v1 + jR[5]*v2;
        jp[2] = jR[6]*v0 + jR[7]*v1 + jR[8]*v2;

        compose(preR[k], prep[k], jR, jp, curR, curp);

        if ((j & 3) == 3) {
            jt = j;
#pragma unroll
            for (int i = 0; i < 9; i++) tR[i] = curR[i];
#pragma unroll
            for (int i = 0; i < 3; i++) tp[i] = curp[i];
        }
    }

    // 3-step inclusive scan over 8 lanes
#pragma unroll
    for (int sft = 1; sft < GRP; sft <<= 1) {
        float fR[9], fp[3];
#pragma unroll
        for (int i = 0; i < 9; i++) fR[i] = __shfl_up(curR[i], sft, GRP);
#pragma unroll
        for (int i = 0; i < 3; i++) fp[i] = __shfl_up(curp[i], sft, GRP);
        if (g >= sft) {
            float nR[9], np[3];
            compose(fR, fp, curR, curp, nR, np);
#pragma unroll
            for (int i = 0; i < 9; i++) curR[i] = nR[i];
#pragma unroll
            for (int i = 0; i < 3; i++) curp[i] = np[i];
        }
    }

    // exclusive prefix E
    float ER[9], Ep[3];
#pragma unroll
    for (int i = 0; i < 9; i++) ER[i] = __shfl_up(curR[i], 1, GRP);
#pragma unroll
    for (int i = 0; i < 3; i++) Ep[i] = __shfl_up(curp[i], 1, GRP);
    if (g == 0) {
        ER[0]=1.f; ER[1]=0.f; ER[2]=0.f; ER[3]=0.f; ER[4]=1.f; ER[5]=0.f;
        ER[6]=0.f; ER[7]=0.f; ER[8]=1.f; Ep[0]=0.f; Ep[1]=0.f; Ep[2]=0.f;
    }

    // tracked output: (E o post'_t) o T_track, direct nt store
    if (jt >= 0) {
        float PR[9], Pp[3];
        compose(ER, Ep, tR, tp, PR, Pp);
        const float4 t0 = s_stat[jt*8+5], t1 = s_stat[jt*8+6], t2 = s_stat[jt*8+7];
        float TtR[9] = {t0.x,t0.y,t0.z, t1.x,t1.y,t1.z, t2.x,t2.y,t2.z};
        float Ttp[3] = {t0.w, t1.w, t2.w};
        float TR[9], Tp[3];
        compose(PR, Pp, TtR, Ttp, TR, Tp);
        f4* td = (f4*)out_track + ((size_t)b * NTRK + (jt >> 2)) * 4;
        __builtin_nontemporal_store((f4){TR[0], TR[1], TR[2], Tp[0]}, &td[0]);
        __builtin_nontemporal_store((f4){TR[3], TR[4], TR[5], Tp[1]}, &td[1]);
        __builtin_nontemporal_store((f4){TR[6], TR[7], TR[8], Tp[2]}, &td[2]);
        __builtin_nontemporal_store((f4){0.f, 0.f, 0.f, 1.f},        &td[3]);
    }

    // finalize pre_j = E o pre'_k into registers (LDS write happens after barrier)
#pragma unroll
    for (int k = 0; k < JPL; k++)
        compose(ER, Ep, preR[k], prep[k], FR[k], Fp[k]);
}

__global__ __launch_bounds__(256, 4) void fk_kernel(
    const float* __restrict__ rev_q,    const float* __restrict__ pri_q,
    const float* __restrict__ p_off,    const float* __restrict__ rpy_off,
    const float* __restrict__ rev_axis, const float* __restrict__ pri_axis,
    const float* __restrict__ p_trk,    const float* __restrict__ rpy_trk,
    float* __restrict__ out_track, float* __restrict__ out_joint)
{
    __shared__ float4 s_stat[NJ * 8];   // 3 KB
    __shared__ f4 s_j[BPB * PAD3];      // 36 KB staging (single buffer)

    const int tid = threadIdx.x;
    const int g   = tid & (GRP - 1);
    const int bb  = tid >> 3;

    // ---- per-block statics ----
    if (tid < NJ) {
        const int j = tid;
        float R[9];
        rpy2R(rpy_off[j*3+0], rpy_off[j*3+1], rpy_off[j*3+2], R);
        s_stat[j*8+0] = make_float4(R[0], R[1], R[2], p_off[j*3+0]);
        s_stat[j*8+1] = make_float4(R[3], R[4], R[5], p_off[j*3+1]);
        s_stat[j*8+2] = make_float4(R[6], R[7], R[8], p_off[j*3+2]);

        float ax = rev_axis[j*3+0], ay = rev_axis[j*3+1], az = rev_axis[j*3+2];
        float n = sqrtf(ax*ax + ay*ay + az*az) + 1e-8f;   // ref: axis/(norm+EPS)
        ax /= n; ay /= n; az /= n;
        s_stat[j*8+3] = make_float4(ax, ay, az, ax*ax + ay*ay + az*az);
        s_stat[j*8+4] = make_float4(pri_axis[j*3+0], pri_axis[j*3+1], pri_axis[j*3+2], 0.f);

        rpy2R(rpy_trk[j*3+0], rpy_trk[j*3+1], rpy_trk[j*3+2], R);
        s_stat[j*8+5] = make_float4(R[0], R[1], R[2], p_trk[j*3+0]);
        s_stat[j*8+6] = make_float4(R[3], R[4], R[5], p_trk[j*3+1]);
        s_stat[j*8+7] = make_float4(R[6], R[7], R[8], p_trk[j*3+2]);
    }
    __syncthreads();

    // prologue: q loads for tile 0
    float qr[JPL], qp[JPL];
    {
        const int b0 = (blockIdx.x * TILES + 0) * BPB + bb;
        const float* rq = rev_q + (size_t)b0 * NJ + 3 * g;
        const float* pq = pri_q + (size_t)b0 * NJ + 3 * g;
#pragma unroll
        for (int k = 0; k < JPL; k++) { qr[k] = rq[k]; qp[k] = pq[k]; }
    }

#pragma unroll
    for (int t = 0; t < TILES; t++) {
        const int tb = blockIdx.x * TILES + t;    // global tile index
        const int b  = tb * BPB + bb;             // this thread's batch

        float FR[JPL][9], Fp[JPL][3];
        tile_compute(b, g, s_stat, qr, qp, out_track, FR, Fp);

        // barrier A (t>0): all waves' flush reads of s_j from tile t-1 done.
        // lgkmcnt(0) only -- no vmcnt drain, tile t-1 stores stay in flight.
        if (t > 0)
            asm volatile("s_waitcnt lgkmcnt(0)\n\ts_barrier" ::: "memory");

        // stage finalized rows
#pragma unroll
        for (int k = 0; k < JPL; k++) {
            f4* dst = &s_j[bb * PAD3 + (3 * g + k) * 3];
            dst[0] = (f4){FR[k][0], FR[k][1], FR[k][2], Fp[k][0]};
            dst[1] = (f4){FR[k][3], FR[k][4], FR[k][5], Fp[k][1]};
            dst[2] = (f4){FR[k][6], FR[k][7], FR[k][8], Fp[k][2]};
        }

        // barrier B: writes visible block-wide (again lgkm only)
        asm volatile("s_waitcnt lgkmcnt(0)\n\ts_barrier" ::: "memory");

        // issue next tile's q loads BEFORE the flush stores so the compiler's
        // wait for them is a counted vmcnt(N), not a store drain
        if (t + 1 < TILES) {
            const int b1 = (tb + 1) * BPB + bb;
            const float* rq = rev_q + (size_t)b1 * NJ + 3 * g;
            const float* pq = pri_q + (size_t)b1 * NJ + 3 * g;
#pragma unroll
            for (int k = 0; k < JPL; k++) { qr[k] = rq[k]; qp[k] = pq[k]; }
        }

        // ---- block-wide coalesced nontemporal flush (3072 f4) ----
        f4* oj = (f4*)out_joint + (size_t)tb * (BPB * NJ * 4);
#pragma unroll
        for (int it = 0; it < 12; it++) {
            int flat = it * 256 + tid;      // 0 .. 3071
            int bI = flat / 96;             // batch within tile (magic-mul)
            int rem = flat - bI * 96;
            int r = rem & 3;
            int jj = rem >> 2;
            f4 v;
            if (r == 3) v = (f4){0.f, 0.f, 0.f, 1.f};
            else        v = s_j[bI * PAD3 + jj * 3 + r];
            __builtin_nontemporal_store(v, &oj[flat]);
        }
    }
}

extern "C" void kernel_launch(void* const* d_in, const int* in_sizes, int n_in,
                              void* d_out, int out_size, void* d_ws, size_t ws_size,
                              hipStream_t stream) {
    const float* rev_q    = (const float*)d_in[0];
    const float* pri_q    = (const float*)d_in[1];
    const float* p_off    = (const float*)d_in[2];
    const float* rpy_off  = (const float*)d_in[3];
    const float* rev_axis = (const float*)d_in[4];
    const float* pri_axis = (const float*)d_in[5];
    const float* p_trk    = (const float*)d_in[6];
    const float* rpy_trk  = (const float*)d_in[7];

    float* out = (float*)d_out;
    float* out_track = out;                           // (B, 6, 4, 4)
    float* out_joint = out + (size_t)NB * NTRK * 16;  // (B, 24, 4, 4)

    dim3 grid(NB / (BPB * TILES)), block(256);        // 1024 blocks = 4/CU
    hipLaunchKernelGGL(fk_kernel, grid, block, 0, stream,
                       rev_q, pri_q, p_off, rpy_off, rev_axis, pri_axis,
                       p_trk, rpy_trk, out_track, out_joint);
}

// Round 8
// 52.253 us; speedup vs baseline: 1.1842x; 1.1842x over previous
//
#include <hip/hip_runtime.h>

#define NB 65536
#define NJ 24
#define NTRK 6
#define GRP 8         // lanes per batch (24/3, no idle lanes)
#define JPL 3         // joints per lane
#define BPB 32        // batches per 256-thread block (8 per wave)

typedef float f4 __attribute__((ext_vector_type(4)));

__device__ __forceinline__ void rpy2R(float r, float p, float y, float* R) {
    float cr = cosf(r), sr = sinf(r);
    float cp = cosf(p), sp = sinf(p);
    float cy = cosf(y), sy = sinf(y);
    R[0] = cy * cp; R[1] = cy * sp * sr - sy * cr; R[2] = cy * sp * cr + sy * sr;
    R[3] = sy * cp; R[4] = sy * sp * sr + cy * cr; R[5] = sy * sp * cr - cy * sr;
    R[6] = -sp;     R[7] = cp * sr;                R[8] = cp * cr;
}

// C = A o B (SE3): Rc = Ra*Rb, pc = Ra*pb + pa.  C must not alias A or B.
__device__ __forceinline__ void compose(const float* Ra, const float* pa,
                                        const float* Rb, const float* pb,
                                        float* Rc, float* pc) {
#pragma unroll
    for (int i = 0; i < 3; i++) {
        float a0 = Ra[i*3+0], a1 = Ra[i*3+1], a2 = Ra[i*3+2];
        Rc[i*3+0] = a0*Rb[0] + a1*Rb[3] + a2*Rb[6];
        Rc[i*3+1] = a0*Rb[1] + a1*Rb[4] + a2*Rb[7];
        Rc[i*3+2] = a0*Rb[2] + a1*Rb[5] + a2*Rb[8];
        pc[i]     = a0*pb[0] + a1*pb[1] + a2*pb[2] + pa[i];
    }
}

__global__ __launch_bounds__(256, 4) void fk_kernel(
    const float* __restrict__ rev_q,    const float* __restrict__ pri_q,
    const float* __restrict__ p_off,    const float* __restrict__ rpy_off,
    const float* __restrict__ rev_axis, const float* __restrict__ pri_axis,
    const float* __restrict__ p_trk,    const float* __restrict__ rpy_trk,
    float* __restrict__ out_track, float* __restrict__ out_joint)
{
    // per joint j, slot j*8+k: 0..2 T_offset rows|p, 3 norm axis|adot,
    // 4 pri_axis, 5..7 T_track rows|p
    __shared__ float4 s_stat[NJ * 8];   // 3 KB; only LDS in the kernel

    const int tid = threadIdx.x;
    const int g   = tid & (GRP - 1);    // lane within batch (owns joints 3g..3g+2)
    const int bb  = tid >> 3;           // batch within block
    const int b   = blockIdx.x * BPB + bb;

    // q loads issued first (stream-once, 12.6 MB total, wave-coalesced)
    const float* rq = rev_q + (size_t)b * NJ + 3 * g;
    const float* pq = pri_q + (size_t)b * NJ + 3 * g;
    float qr[JPL] = {rq[0], rq[1], rq[2]};
    float qp[JPL] = {pq[0], pq[1], pq[2]};

    // ---- per-block statics (tiny, L2-hot after first blocks) ----
    if (tid < NJ) {
        const int j = tid;
        float R[9];
        rpy2R(rpy_off[j*3+0], rpy_off[j*3+1], rpy_off[j*3+2], R);
        s_stat[j*8+0] = make_float4(R[0], R[1], R[2], p_off[j*3+0]);
        s_stat[j*8+1] = make_float4(R[3], R[4], R[5], p_off[j*3+1]);
        s_stat[j*8+2] = make_float4(R[6], R[7], R[8], p_off[j*3+2]);

        float ax = rev_axis[j*3+0], ay = rev_axis[j*3+1], az = rev_axis[j*3+2];
        float n = sqrtf(ax*ax + ay*ay + az*az) + 1e-8f;   // ref: axis/(norm+EPS)
        ax /= n; ay /= n; az /= n;
        s_stat[j*8+3] = make_float4(ax, ay, az, ax*ax + ay*ay + az*az);
        s_stat[j*8+4] = make_float4(pri_axis[j*3+0], pri_axis[j*3+1], pri_axis[j*3+2], 0.f);

        rpy2R(rpy_trk[j*3+0], rpy_trk[j*3+1], rpy_trk[j*3+2], R);
        s_stat[j*8+5] = make_float4(R[0], R[1], R[2], p_trk[j*3+0]);
        s_stat[j*8+6] = make_float4(R[3], R[4], R[5], p_trk[j*3+1]);
        s_stat[j*8+7] = make_float4(R[6], R[7], R[8], p_trk[j*3+2]);
    }
    __syncthreads();   // the only block-wide barrier

    // ---- local serial pass over this lane's 3 joints (from identity) ----
    float preR[JPL][9], prep[JPL][3];   // local pre' (pre-prefix JointSE3)
    float curR[9], curp[3];             // running local product -> lane product
    float tR[9], tp[3];                 // local post at this lane's tracked joint
    int jt = -1;

#pragma unroll
    for (int k = 0; k < JPL; k++) {
        const int j = 3 * g + k;
        const float4 s0 = s_stat[j*8+0], s1 = s_stat[j*8+1], s2 = s_stat[j*8+2];
        const float4 s3 = s_stat[j*8+3], s4 = s_stat[j*8+4];
        float ToR[9] = {s0.x,s0.y,s0.z, s1.x,s1.y,s1.z, s2.x,s2.y,s2.z};
        float Top[3] = {s0.w, s1.w, s2.w};

        if (k == 0) {
#pragma unroll
            for (int i = 0; i < 9; i++) preR[0][i] = ToR[i];
#pragma unroll
            for (int i = 0; i < 3; i++) prep[0][i] = Top[i];
        } else {
            compose(curR, curp, ToR, Top, preR[k], prep[k]);
        }

        // joint transform: Rodrigues + prismatic
        float s = __sinf(qr[k]), c = __cosf(qr[k]), c1 = 1.0f - c;
        const float ax = s3.x, ay = s3.y, az = s3.z, adot = s3.w;
        float jR[9];
        jR[0] = 1.f + c1*(ax*ax - adot);  jR[1] = -s*az + c1*ax*ay;        jR[2] =  s*ay + c1*ax*az;
        jR[3] =  s*az + c1*ax*ay;         jR[4] = 1.f + c1*(ay*ay - adot); jR[5] = -s*ax + c1*ay*az;
        jR[6] = -s*ay + c1*ax*az;         jR[7] =  s*ax + c1*ay*az;        jR[8] = 1.f + c1*(az*az - adot);
        float v0 = qp[k]*s4.x, v1 = qp[k]*s4.y, v2 = qp[k]*s4.z;
        float jp[3];
        jp[0] = jR[0]*v0 + jR[1]*v1 + jR[2]*v2;
        jp[1] = jR[3]*v0 + jR[4]*v1 + jR[5]*v2;
        jp[2] = jR[6]*v0 + jR[7]*v1 + jR[8]*v2;

        compose(preR[k], prep[k], jR, jp, curR, curp);   // cur = pre' o Tj

        if ((j & 3) == 3) {   // lane's tracked joint (at most one per lane)
            jt = j;
#pragma unroll
            for (int i = 0; i < 9; i++) tR[i] = curR[i];
#pragma unroll
            for (int i = 0; i < 3; i++) tp[i] = curp[i];
        }
    }

    // ---- 3-step inclusive scan of lane products over 8 lanes ----
#pragma unroll
    for (int sft = 1; sft < GRP; sft <<= 1) {
        float fR[9], fp[3];
#pragma unroll
        for (int i = 0; i < 9; i++) fR[i] = __shfl_up(curR[i], sft, GRP);
#pragma unroll
        for (int i = 0; i < 3; i++) fp[i] = __shfl_up(curp[i], sft, GRP);
        if (g >= sft) {
            float nR[9], np[3];
            compose(fR, fp, curR, curp, nR, np);   // earlier lanes on the left
#pragma unroll
            for (int i = 0; i < 9; i++) curR[i] = nR[i];
#pragma unroll
            for (int i = 0; i < 3; i++) curp[i] = np[i];
        }
    }

    // ---- exclusive prefix E (identity for lane 0) ----
    float ER[9], Ep[3];
#pragma unroll
    for (int i = 0; i < 9; i++) ER[i] = __shfl_up(curR[i], 1, GRP);
#pragma unroll
    for (int i = 0; i < 3; i++) Ep[i] = __shfl_up(curp[i], 1, GRP);
    if (g == 0) {
        ER[0]=1.f; ER[1]=0.f; ER[2]=0.f; ER[3]=0.f; ER[4]=1.f; ER[5]=0.f;
        ER[6]=0.f; ER[7]=0.f; ER[8]=1.f; Ep[0]=0.f; Ep[1]=0.f; Ep[2]=0.f;
    }

    // ---- tracked output: (E o post'_t) o T_track, direct plain store ----
    if (jt >= 0) {
        float PR[9], Pp[3];
        compose(ER, Ep, tR, tp, PR, Pp);
        const float4 t0 = s_stat[jt*8+5], t1 = s_stat[jt*8+6], t2 = s_stat[jt*8+7];
        float TtR[9] = {t0.x,t0.y,t0.z, t1.x,t1.y,t1.z, t2.x,t2.y,t2.z};
        float Ttp[3] = {t0.w, t1.w, t2.w};
        float TR[9], Tp[3];
        compose(PR, Pp, TtR, Ttp, TR, Tp);
        f4* td = (f4*)out_track + ((size_t)b * NTRK + (jt >> 2)) * 4;
        td[0] = (f4){TR[0], TR[1], TR[2], Tp[0]};
        td[1] = (f4){TR[3], TR[4], TR[5], Tp[1]};
        td[2] = (f4){TR[6], TR[7], TR[8], Tp[2]};
        td[3] = (f4){0.f, 0.f, 0.f, 1.f};
    }

    // ---- finalize pre_j = E o pre'_k, store DIRECT from registers ----
    // Lane's 3 matrices are contiguous 192 B at (b*24 + 3g)*64; each 64 B
    // line gets 4 consecutive f4 stores from this lane -> L2 merges to full
    // lines. No LDS staging, no barrier: waves retire independently, store
    // drain overlaps other waves' compute.
    f4* oj = (f4*)out_joint + ((size_t)b * NJ + 3 * g) * 4;
#pragma unroll
    for (int k = 0; k < JPL; k++) {
        float FR[9], Fp[3];
        compose(ER, Ep, preR[k], prep[k], FR, Fp);
        oj[k*4+0] = (f4){FR[0], FR[1], FR[2], Fp[0]};
        oj[k*4+1] = (f4){FR[3], FR[4], FR[5], Fp[1]};
        oj[k*4+2] = (f4){FR[6], FR[7], FR[8], Fp[2]};
        oj[k*4+3] = (f4){0.f, 0.f, 0.f, 1.f};
    }
}

extern "C" void kernel_launch(void* const* d_in, const int* in_sizes, int n_in,
                              void* d_out, int out_size, void* d_ws, size_t ws_size,
                              hipStream_t stream) {
    const float* rev_q    = (const float*)d_in[0];
    const float* pri_q    = (const float*)d_in[1];
    const float* p_off    = (const float*)d_in[2];
    const float* rpy_off  = (const float*)d_in[3];
    const float* rev_axis = (const float*)d_in[4];
    const float* pri_axis = (const float*)d_in[5];
    const float* p_trk    = (const float*)d_in[6];
    const float* rpy_trk  = (const float*)d_in[7];

    float* out = (float*)d_out;
    float* out_track = out;                           // (B, 6, 4, 4)
    float* out_joint = out + (size_t)NB * NTRK * 16;  // (B, 24, 4, 4)

    dim3 grid(NB / BPB), block(256);
    hipLaunchKernelGGL(fk_kernel, grid, block, 0, stream,
                       rev_q, pri_q, p_off, rpy_off, rev_axis, pri_axis,
                       p_trk, rpy_trk, out_track, out_joint);
}

// Round 9
// 36.358 us; speedup vs baseline: 1.7019x; 1.4372x over previous
//
#include <hip/hip_runtime.h>

#define NB 65536
#define NJ 24
#define NTRK 6
#define GRP 8         // lanes per batch (24/3, no idle lanes)
#define JPL 3         // joints per lane
#define BPB 8         // batches per 64-thread (1-wave) block
#define PAD3 72       // f4 per batch in LDS: 24 joints x 3 rows

typedef float f4 __attribute__((ext_vector_type(4)));

__device__ __forceinline__ void rpy2R(float r, float p, float y, float* R) {
    float cr = cosf(r), sr = sinf(r);
    float cp = cosf(p), sp = sinf(p);
    float cy = cosf(y), sy = sinf(y);
    R[0] = cy * cp; R[1] = cy * sp * sr - sy * cr; R[2] = cy * sp * cr + sy * sr;
    R[3] = sy * cp; R[4] = sy * sp * sr + cy * cr; R[5] = sy * sp * cr - cy * sr;
    R[6] = -sp;     R[7] = cp * sr;                R[8] = cp * cr;
}

// C = A o B (SE3): Rc = Ra*Rb, pc = Ra*pb + pa.  C must not alias A or B.
__device__ __forceinline__ void compose(const float* Ra, const float* pa,
                                        const float* Rb, const float* pb,
                                        float* Rc, float* pc) {
#pragma unroll
    for (int i = 0; i < 3; i++) {
        float a0 = Ra[i*3+0], a1 = Ra[i*3+1], a2 = Ra[i*3+2];
        Rc[i*3+0] = a0*Rb[0] + a1*Rb[3] + a2*Rb[6];
        Rc[i*3+1] = a0*Rb[1] + a1*Rb[4] + a2*Rb[7];
        Rc[i*3+2] = a0*Rb[2] + a1*Rb[5] + a2*Rb[8];
        pc[i]     = a0*pb[0] + a1*pb[1] + a2*pb[2] + pa[i];
    }
}

// Single-wave workgroup: 8 batches/block, no inter-wave coupling -> blocks
// retire & get replaced continuously, so the CU always has a mix of
// computing and flushing waves (continuous HBM store stream).
__global__ __launch_bounds__(64, 4) void fk_kernel(
    const float* __restrict__ rev_q,    const float* __restrict__ pri_q,
    const float* __restrict__ p_off,    const float* __restrict__ rpy_off,
    const float* __restrict__ rev_axis, const float* __restrict__ pri_axis,
    const float* __restrict__ p_trk,    const float* __restrict__ rpy_trk,
    float* __restrict__ out_track, float* __restrict__ out_joint)
{
    // per joint j, slot j*8+k: 0..2 T_offset rows|p, 3 norm axis|adot,
    // 4 pri_axis, 5..7 T_track rows|p
    __shared__ float4 s_stat[NJ * 8];   // 3 KB
    __shared__ f4 s_j[BPB * PAD3];      // 9.2 KB staging (wave-private)

    const int tid = threadIdx.x;        // 0..63
    const int g   = tid & (GRP - 1);    // lane within batch (owns joints 3g..3g+2)
    const int bb  = tid >> 3;           // batch within block (0..7)
    const int b   = blockIdx.x * BPB + bb;

    // q loads issued first (stream-once; wave covers 768 B contiguous)
    const float* rq = rev_q + (size_t)b * NJ + 3 * g;
    const float* pq = pri_q + (size_t)b * NJ + 3 * g;
    float qr[JPL] = {rq[0], rq[1], rq[2]};
    float qp[JPL] = {pq[0], pq[1], pq[2]};

    // ---- per-block statics (24 lanes; L2-hot) ----
    if (tid < NJ) {
        const int j = tid;
        float R[9];
        rpy2R(rpy_off[j*3+0], rpy_off[j*3+1], rpy_off[j*3+2], R);
        s_stat[j*8+0] = make_float4(R[0], R[1], R[2], p_off[j*3+0]);
        s_stat[j*8+1] = make_float4(R[3], R[4], R[5], p_off[j*3+1]);
        s_stat[j*8+2] = make_float4(R[6], R[7], R[8], p_off[j*3+2]);

        float ax = rev_axis[j*3+0], ay = rev_axis[j*3+1], az = rev_axis[j*3+2];
        float n = sqrtf(ax*ax + ay*ay + az*az) + 1e-8f;   // ref: axis/(norm+EPS)
        ax /= n; ay /= n; az /= n;
        s_stat[j*8+3] = make_float4(ax, ay, az, ax*ax + ay*ay + az*az);
        s_stat[j*8+4] = make_float4(pri_axis[j*3+0], pri_axis[j*3+1], pri_axis[j*3+2], 0.f);

        rpy2R(rpy_trk[j*3+0], rpy_trk[j*3+1], rpy_trk[j*3+2], R);
        s_stat[j*8+5] = make_float4(R[0], R[1], R[2], p_trk[j*3+0]);
        s_stat[j*8+6] = make_float4(R[3], R[4], R[5], p_trk[j*3+1]);
        s_stat[j*8+7] = make_float4(R[6], R[7], R[8], p_trk[j*3+2]);
    }
    __syncthreads();    // single-wave workgroup: effectively just a waitcnt

    // ---- local serial pass over this lane's 3 joints (from identity) ----
    float preR[JPL][9], prep[JPL][3];   // local pre' (pre-prefix JointSE3)
    float curR[9], curp[3];             // running local product -> lane product
    float tR[9], tp[3];                 // local post at this lane's tracked joint
    int jt = -1;

#pragma unroll
    for (int k = 0; k < JPL; k++) {
        const int j = 3 * g + k;
        const float4 s0 = s_stat[j*8+0], s1 = s_stat[j*8+1], s2 = s_stat[j*8+2];
        const float4 s3 = s_stat[j*8+3], s4 = s_stat[j*8+4];
        float ToR[9] = {s0.x,s0.y,s0.z, s1.x,s1.y,s1.z, s2.x,s2.y,s2.z};
        float Top[3] = {s0.w, s1.w, s2.w};

        if (k == 0) {
#pragma unroll
            for (int i = 0; i < 9; i++) preR[0][i] = ToR[i];
#pragma unroll
            for (int i = 0; i < 3; i++) prep[0][i] = Top[i];
        } else {
            compose(curR, curp, ToR, Top, preR[k], prep[k]);
        }

        // joint transform: Rodrigues + prismatic
        float s = __sinf(qr[k]), c = __cosf(qr[k]), c1 = 1.0f - c;
        const float ax = s3.x, ay = s3.y, az = s3.z, adot = s3.w;
        float jR[9];
        jR[0] = 1.f + c1*(ax*ax - adot);  jR[1] = -s*az + c1*ax*ay;        jR[2] =  s*ay + c1*ax*az;
        jR[3] =  s*az + c1*ax*ay;         jR[4] = 1.f + c1*(ay*ay - adot); jR[5] = -s*ax + c1*ay*az;
        jR[6] = -s*ay + c1*ax*az;         jR[7] =  s*ax + c1*ay*az;        jR[8] = 1.f + c1*(az*az - adot);
        float v0 = qp[k]*s4.x, v1 = qp[k]*s4.y, v2 = qp[k]*s4.z;
        float jp[3];
        jp[0] = jR[0]*v0 + jR[1]*v1 + jR[2]*v2;
        jp[1] = jR[3]*v0 + jR[4]*v1 + jR[5]*v2;
        jp[2] = jR[6]*v0 + jR[7]*v1 + jR[8]*v2;

        compose(preR[k], prep[k], jR, jp, curR, curp);   // cur = pre' o Tj

        if ((j & 3) == 3) {   // lane's tracked joint (at most one per lane)
            jt = j;
#pragma unroll
            for (int i = 0; i < 9; i++) tR[i] = curR[i];
#pragma unroll
            for (int i = 0; i < 3; i++) tp[i] = curp[i];
        }
    }

    // ---- 3-step inclusive scan of lane products over 8 lanes ----
#pragma unroll
    for (int sft = 1; sft < GRP; sft <<= 1) {
        float fR[9], fp[3];
#pragma unroll
        for (int i = 0; i < 9; i++) fR[i] = __shfl_up(curR[i], sft, GRP);
#pragma unroll
        for (int i = 0; i < 3; i++) fp[i] = __shfl_up(curp[i], sft, GRP);
        if (g >= sft) {
            float nR[9], np[3];
            compose(fR, fp, curR, curp, nR, np);   // earlier lanes on the left
#pragma unroll
            for (int i = 0; i < 9; i++) curR[i] = nR[i];
#pragma unroll
            for (int i = 0; i < 3; i++) curp[i] = np[i];
        }
    }

    // ---- exclusive prefix E (identity for lane 0) ----
    float ER[9], Ep[3];
#pragma unroll
    for (int i = 0; i < 9; i++) ER[i] = __shfl_up(curR[i], 1, GRP);
#pragma unroll
    for (int i = 0; i < 3; i++) Ep[i] = __shfl_up(curp[i], 1, GRP);
    if (g == 0) {
        ER[0]=1.f; ER[1]=0.f; ER[2]=0.f; ER[3]=0.f; ER[4]=1.f; ER[5]=0.f;
        ER[6]=0.f; ER[7]=0.f; ER[8]=1.f; Ep[0]=0.f; Ep[1]=0.f; Ep[2]=0.f;
    }

    // ---- tracked output: (E o post'_t) o T_track, direct store ----
    if (jt >= 0) {
        float PR[9], Pp[3];
        compose(ER, Ep, tR, tp, PR, Pp);
        const float4 t0 = s_stat[jt*8+5], t1 = s_stat[jt*8+6], t2 = s_stat[jt*8+7];
        float TtR[9] = {t0.x,t0.y,t0.z, t1.x,t1.y,t1.z, t2.x,t2.y,t2.z};
        float Ttp[3] = {t0.w, t1.w, t2.w};
        float TR[9], Tp[3];
        compose(PR, Pp, TtR, Ttp, TR, Tp);
        f4* td = (f4*)out_track + ((size_t)b * NTRK + (jt >> 2)) * 4;
        td[0] = (f4){TR[0], TR[1], TR[2], Tp[0]};
        td[1] = (f4){TR[3], TR[4], TR[5], Tp[1]};
        td[2] = (f4){TR[6], TR[7], TR[8], Tp[2]};
        td[3] = (f4){0.f, 0.f, 0.f, 1.f};
    }

    // ---- finalize pre_j = E o pre'_k, stage 3 rows into LDS ----
#pragma unroll
    for (int k = 0; k < JPL; k++) {
        float FR[9], Fp[3];
        compose(ER, Ep, preR[k], prep[k], FR, Fp);
        f4* dst = &s_j[bb * PAD3 + (3 * g + k) * 3];
        dst[0] = (f4){FR[0], FR[1], FR[2], Fp[0]};
        dst[1] = (f4){FR[3], FR[4], FR[5], Fp[1]};
        dst[2] = (f4){FR[6], FR[7], FR[8], Fp[2]};
    }
    __syncthreads();    // wave-local; compiles to a waitcnt for 1-wave group

    // ---- coalesced nontemporal flush: 49 KB contiguous per block ----
    f4* oj = (f4*)out_joint + (size_t)blockIdx.x * (BPB * NJ * 4);
#pragma unroll
    for (int it = 0; it < 12; it++) {
        int flat = it * 64 + tid;       // 0 .. 767 output f4 index
        int bI = flat / 96;             // batch within block (magic-mul)
        int rem = flat - bI * 96;
        int r = rem & 3;                // row within 4x4
        int jj = rem >> 2;              // joint
        f4 v;
        if (r == 3) v = (f4){0.f, 0.f, 0.f, 1.f};
        else        v = s_j[bI * PAD3 + jj * 3 + r];
        __builtin_nontemporal_store(v, &oj[flat]);
    }
}

extern "C" void kernel_launch(void* const* d_in, const int* in_sizes, int n_in,
                              void* d_out, int out_size, void* d_ws, size_t ws_size,
                              hipStream_t stream) {
    const float* rev_q    = (const float*)d_in[0];
    const float* pri_q    = (const float*)d_in[1];
    const float* p_off    = (const float*)d_in[2];
    const float* rpy_off  = (const float*)d_in[3];
    const float* rev_axis = (const float*)d_in[4];
    const float* pri_axis = (const float*)d_in[5];
    const float* p_trk    = (const float*)d_in[6];
    const float* rpy_trk  = (const float*)d_in[7];

    float* out = (float*)d_out;
    float* out_track = out;                           // (B, 6, 4, 4)
    float* out_joint = out + (size_t)NB * NTRK * 16;  // (B, 24, 4, 4)

    dim3 grid(NB / BPB), block(64);                   // 8192 one-wave blocks
    hipLaunchKernelGGL(fk_kernel, grid, block, 0, stream,
                       rev_q, pri_q, p_off, rpy_off, rev_axis, pri_axis,
                       p_trk, rpy_trk, out_track, out_joint);
}

// Round 10
// 35.348 us; speedup vs baseline: 1.7506x; 1.0286x over previous
//
#include <hip/hip_runtime.h>

#define NB 65536
#define NJ 24
#define NTRK 6
#define GRP 8         // lanes per batch (24/3, no idle lanes)
#define JPL 3         // joints per lane
#define BPB 32        // batches per 256-thread block (8 per wave)
#define PAD3 72       // f4 per batch in LDS: 24 joints x 3 rows (bottom row constant)

typedef float f4 __attribute__((ext_vector_type(4)));

__device__ __forceinline__ void rpy2R(float r, float p, float y, float* R) {
    float cr = cosf(r), sr = sinf(r);
    float cp = cosf(p), sp = sinf(p);
    float cy = cosf(y), sy = sinf(y);
    R[0] = cy * cp; R[1] = cy * sp * sr - sy * cr; R[2] = cy * sp * cr + sy * sr;
    R[3] = sy * cp; R[4] = sy * sp * sr + cy * cr; R[5] = sy * sp * cr - cy * sr;
    R[6] = -sp;     R[7] = cp * sr;                R[8] = cp * cr;
}

// C = A o B (SE3): Rc = Ra*Rb, pc = Ra*pb + pa.  C must not alias A or B.
__device__ __forceinline__ void compose(const float* Ra, const float* pa,
                                        const float* Rb, const float* pb,
                                        float* Rc, float* pc) {
#pragma unroll
    for (int i = 0; i < 3; i++) {
        float a0 = Ra[i*3+0], a1 = Ra[i*3+1], a2 = Ra[i*3+2];
        Rc[i*3+0] = a0*Rb[0] + a1*Rb[3] + a2*Rb[6];
        Rc[i*3+1] = a0*Rb[1] + a1*Rb[4] + a2*Rb[7];
        Rc[i*3+2] = a0*Rb[2] + a1*Rb[5] + a2*Rb[8];
        pc[i]     = a0*pb[0] + a1*pb[1] + a2*pb[2] + pa[i];
    }
}

__global__ __launch_bounds__(256, 4) void fk_kernel(
    const float* __restrict__ rev_q,    const float* __restrict__ pri_q,
    const float* __restrict__ p_off,    const float* __restrict__ rpy_off,
    const float* __restrict__ rev_axis, const float* __restrict__ pri_axis,
    const float* __restrict__ p_trk,    const float* __restrict__ rpy_trk,
    float* __restrict__ out_track, float* __restrict__ out_joint)
{
    // per joint j, slot j*8+k: 0..2 T_offset rows|p, 3 norm axis|adot,
    // 4 pri_axis, 5..7 T_track rows|p
    __shared__ float4 s_stat[NJ * 8];   // 3 KB
    __shared__ f4 s_j[BPB * PAD3];      // 36 KB (3 rows per matrix)

    const int tid = threadIdx.x;
    const int g   = tid & (GRP - 1);    // lane within batch (owns joints 3g..3g+2)
    const int bb  = tid >> 3;           // batch within block
    const int b   = blockIdx.x * BPB + bb;

    // q loads issued first (stream-once, 12.6 MB total)
    const float* rq = rev_q + (size_t)b * NJ + 3 * g;
    const float* pq = pri_q + (size_t)b * NJ + 3 * g;
    float qr[JPL] = {rq[0], rq[1], rq[2]};
    float qp[JPL] = {pq[0], pq[1], pq[2]};

    // ---- per-block statics (tiny, L2-hot after first blocks) ----
    if (tid < NJ) {
        const int j = tid;
        float R[9];
        rpy2R(rpy_off[j*3+0], rpy_off[j*3+1], rpy_off[j*3+2], R);
        s_stat[j*8+0] = make_float4(R[0], R[1], R[2], p_off[j*3+0]);
        s_stat[j*8+1] = make_float4(R[3], R[4], R[5], p_off[j*3+1]);
        s_stat[j*8+2] = make_float4(R[6], R[7], R[8], p_off[j*3+2]);

        float ax = rev_axis[j*3+0], ay = rev_axis[j*3+1], az = rev_axis[j*3+2];
        float n = sqrtf(ax*ax + ay*ay + az*az) + 1e-8f;   // ref: axis/(norm+EPS)
        ax /= n; ay /= n; az /= n;
        s_stat[j*8+3] = make_float4(ax, ay, az, ax*ax + ay*ay + az*az);
        s_stat[j*8+4] = make_float4(pri_axis[j*3+0], pri_axis[j*3+1], pri_axis[j*3+2], 0.f);

        rpy2R(rpy_trk[j*3+0], rpy_trk[j*3+1], rpy_trk[j*3+2], R);
        s_stat[j*8+5] = make_float4(R[0], R[1], R[2], p_trk[j*3+0]);
        s_stat[j*8+6] = make_float4(R[3], R[4], R[5], p_trk[j*3+1]);
        s_stat[j*8+7] = make_float4(R[6], R[7], R[8], p_trk[j*3+2]);
    }
    __syncthreads();

    // ---- local serial pass over this lane's 3 joints (from identity) ----
    float preR[JPL][9], prep[JPL][3];   // local pre' (pre-prefix JointSE3)
    float curR[9], curp[3];             // running local product -> lane product
    float tR[9], tp[3];                 // local post at this lane's tracked joint
    int jt = -1;

#pragma unroll
    for (int k = 0; k < JPL; k++) {
        const int j = 3 * g + k;
        const float4 s0 = s_stat[j*8+0], s1 = s_stat[j*8+1], s2 = s_stat[j*8+2];
        const float4 s3 = s_stat[j*8+3], s4 = s_stat[j*8+4];
        float ToR[9] = {s0.x,s0.y,s0.z, s1.x,s1.y,s1.z, s2.x,s2.y,s2.z};
        float Top[3] = {s0.w, s1.w, s2.w};

        if (k == 0) {
#pragma unroll
            for (int i = 0; i < 9; i++) preR[0][i] = ToR[i];
#pragma unroll
            for (int i = 0; i < 3; i++) prep[0][i] = Top[i];
        } else {
            compose(curR, curp, ToR, Top, preR[k], prep[k]);
        }

        // joint transform: Rodrigues + prismatic
        float s = __sinf(qr[k]), c = __cosf(qr[k]), c1 = 1.0f - c;
        const float ax = s3.x, ay = s3.y, az = s3.z, adot = s3.w;
        float jR[9];
        jR[0] = 1.f + c1*(ax*ax - adot);  jR[1] = -s*az + c1*ax*ay;        jR[2] =  s*ay + c1*ax*az;
        jR[3] =  s*az + c1*ax*ay;         jR[4] = 1.f + c1*(ay*ay - adot); jR[5] = -s*ax + c1*ay*az;
        jR[6] = -s*ay + c1*ax*az;         jR[7] =  s*ax + c1*ay*az;        jR[8] = 1.f + c1*(az*az - adot);
        float v0 = qp[k]*s4.x, v1 = qp[k]*s4.y, v2 = qp[k]*s4.z;
        float jp[3];
        jp[0] = jR[0]*v0 + jR[1]*v1 + jR[2]*v2;
        jp[1] = jR[3]*v0 + jR[4]*v1 + jR[5]*v2;
        jp[2] = jR[6]*v0 + jR[7]*v1 + jR[8]*v2;

        compose(preR[k], prep[k], jR, jp, curR, curp);   // cur = pre' o Tj

        if ((j & 3) == 3) {   // lane's tracked joint (at most one per lane)
            jt = j;
#pragma unroll
            for (int i = 0; i < 9; i++) tR[i] = curR[i];
#pragma unroll
            for (int i = 0; i < 3; i++) tp[i] = curp[i];
        }
    }

    // ---- 3-step inclusive scan of lane products over 8 lanes ----
#pragma unroll
    for (int sft = 1; sft < GRP; sft <<= 1) {
        float fR[9], fp[3];
#pragma unroll
        for (int i = 0; i < 9; i++) fR[i] = __shfl_up(curR[i], sft, GRP);
#pragma unroll
        for (int i = 0; i < 3; i++) fp[i] = __shfl_up(curp[i], sft, GRP);
        if (g >= sft) {
            float nR[9], np[3];
            compose(fR, fp, curR, curp, nR, np);   // earlier lanes on the left
#pragma unroll
            for (int i = 0; i < 9; i++) curR[i] = nR[i];
#pragma unroll
            for (int i = 0; i < 3; i++) curp[i] = np[i];
        }
    }

    // ---- exclusive prefix E (identity for lane 0) ----
    float ER[9], Ep[3];
#pragma unroll
    for (int i = 0; i < 9; i++) ER[i] = __shfl_up(curR[i], 1, GRP);
#pragma unroll
    for (int i = 0; i < 3; i++) Ep[i] = __shfl_up(curp[i], 1, GRP);
    if (g == 0) {
        ER[0]=1.f; ER[1]=0.f; ER[2]=0.f; ER[3]=0.f; ER[4]=1.f; ER[5]=0.f;
        ER[6]=0.f; ER[7]=0.f; ER[8]=1.f; Ep[0]=0.f; Ep[1]=0.f; Ep[2]=0.f;
    }

    // ---- tracked output: (E o post'_t) o T_track, stored direct (plain) ----
    if (jt >= 0) {
        float PR[9], Pp[3];
        compose(ER, Ep, tR, tp, PR, Pp);
        const float4 t0 = s_stat[jt*8+5], t1 = s_stat[jt*8+6], t2 = s_stat[jt*8+7];
        float TtR[9] = {t0.x,t0.y,t0.z, t1.x,t1.y,t1.z, t2.x,t2.y,t2.z};
        float Ttp[3] = {t0.w, t1.w, t2.w};
        float TR[9], Tp[3];
        compose(PR, Pp, TtR, Ttp, TR, Tp);
        float4* td = (float4*)out_track + ((size_t)b * NTRK + (jt >> 2)) * 4;
        td[0] = make_float4(TR[0], TR[1], TR[2], Tp[0]);
        td[1] = make_float4(TR[3], TR[4], TR[5], Tp[1]);
        td[2] = make_float4(TR[6], TR[7], TR[8], Tp[2]);
        td[3] = make_float4(0.f, 0.f, 0.f, 1.f);
    }

    // ---- finalize pre_j = E o pre'_k, stage 3 rows into LDS ----
#pragma unroll
    for (int k = 0; k < JPL; k++) {
        float FR[9], Fp[3];
        compose(ER, Ep, preR[k], prep[k], FR, Fp);
        f4* dst = &s_j[bb * PAD3 + (3 * g + k) * 3];
        dst[0] = (f4){FR[0], FR[1], FR[2], Fp[0]};
        dst[1] = (f4){FR[3], FR[4], FR[5], Fp[1]};
        dst[2] = (f4){FR[6], FR[7], FR[8], Fp[2]};
    }
    __syncthreads();

    // ---- coalesced PLAIN flush: dirty poison lines in L2 get overwritten
    // in place (single eviction), instead of nt write-around forcing the
    // stale line's writeback on top of ours. Bottom rows from immediates.
    f4* oj = (f4*)out_joint + (size_t)blockIdx.x * (BPB * NJ * 4);
#pragma unroll
    for (int it = 0; it < 12; it++) {
        int flat = it * 256 + tid;          // 0 .. 3071 output f4 index
        int bI = flat / 96;                 // batch within block (magic-mul)
        int rem = flat - bI * 96;
        int r = rem & 3;                    // row within 4x4
        int jj = rem >> 2;                  // joint
        f4 v;
        if (r == 3) v = (f4){0.f, 0.f, 0.f, 1.f};
        else        v = s_j[bI * PAD3 + jj * 3 + r];
        oj[flat] = v;
    }
}

extern "C" void kernel_launch(void* const* d_in, const int* in_sizes, int n_in,
                              void* d_out, int out_size, void* d_ws, size_t ws_size,
                              hipStream_t stream) {
    const float* rev_q    = (const float*)d_in[0];
    const float* pri_q    = (const float*)d_in[1];
    const float* p_off    = (const float*)d_in[2];
    const float* rpy_off  = (const float*)d_in[3];
    const float* rev_axis = (const float*)d_in[4];
    const float* pri_axis = (const float*)d_in[5];
    const float* p_trk    = (const float*)d_in[6];
    const float* rpy_trk  = (const float*)d_in[7];

    float* out = (float*)d_out;
    float* out_track = out;                           // (B, 6, 4, 4)
    float* out_joint = out + (size_t)NB * NTRK * 16;  // (B, 24, 4, 4)

    dim3 grid(NB / BPB), block(256);
    hipLaunchKernelGGL(fk_kernel, grid, block, 0, stream,
                       rev_q, pri_q, p_off, rpy_off, rev_axis, pri_axis,
                       p_trk, rpy_trk, out_track, out_joint);
}

// Round 11
// 33.652 us; speedup vs baseline: 1.8387x; 1.0504x over previous
//
#include <hip/hip_runtime.h>

#define NB 65536
#define NJ 24
#define NTRK 6
#define GRP 8         // lanes per batch (24/3, no idle lanes)
#define JPL 3         // joints per lane
#define BPB 32        // batches per 256-thread block (8 per wave)
#define PAD3 72       // f4 per batch in LDS: 24 joints x 3 rows (bottom row constant)
#define NXCD 8
#define NWG  (NB / BPB)   // 2048 blocks; 2048 % 8 == 0 -> simple swizzle bijective

typedef float f4 __attribute__((ext_vector_type(4)));

__device__ __forceinline__ void rpy2R(float r, float p, float y, float* R) {
    float cr = cosf(r), sr = sinf(r);
    float cp = cosf(p), sp = sinf(p);
    float cy = cosf(y), sy = sinf(y);
    R[0] = cy * cp; R[1] = cy * sp * sr - sy * cr; R[2] = cy * sp * cr + sy * sr;
    R[3] = sy * cp; R[4] = sy * sp * sr + cy * cr; R[5] = sy * sp * cr - cy * sr;
    R[6] = -sp;     R[7] = cp * sr;                R[8] = cp * cr;
}

// C = A o B (SE3): Rc = Ra*Rb, pc = Ra*pb + pa.  C must not alias A or B.
__device__ __forceinline__ void compose(const float* Ra, const float* pa,
                                        const float* Rb, const float* pb,
                                        float* Rc, float* pc) {
#pragma unroll
    for (int i = 0; i < 3; i++) {
        float a0 = Ra[i*3+0], a1 = Ra[i*3+1], a2 = Ra[i*3+2];
        Rc[i*3+0] = a0*Rb[0] + a1*Rb[3] + a2*Rb[6];
        Rc[i*3+1] = a0*Rb[1] + a1*Rb[4] + a2*Rb[7];
        Rc[i*3+2] = a0*Rb[2] + a1*Rb[5] + a2*Rb[8];
        pc[i]     = a0*pb[0] + a1*pb[1] + a2*pb[2] + pa[i];
    }
}

__global__ __launch_bounds__(256, 4) void fk_kernel(
    const float* __restrict__ rev_q,    const float* __restrict__ pri_q,
    const float* __restrict__ p_off,    const float* __restrict__ rpy_off,
    const float* __restrict__ rev_axis, const float* __restrict__ pri_axis,
    const float* __restrict__ p_trk,    const float* __restrict__ rpy_trk,
    float* __restrict__ out_track, float* __restrict__ out_joint)
{
    // per joint j, slot j*8+k: 0..2 T_offset rows|p, 3 norm axis|adot,
    // 4 pri_axis, 5..7 T_track rows|p
    __shared__ float4 s_stat[NJ * 8];   // 3 KB
    __shared__ f4 s_j[BPB * PAD3];      // 36 KB (3 rows per matrix)

    // XCD-chunked swizzle: blocks dispatched round-robin across 8 XCDs;
    // remap so each XCD works a contiguous ~12 MB output region -> its L2
    // accumulates/drains monotonic dirty-line streams.
    const int wg = (int)blockIdx.x;
    const int swz = (wg % NXCD) * (NWG / NXCD) + wg / NXCD;

    const int tid = threadIdx.x;
    const int g   = tid & (GRP - 1);    // lane within batch (owns joints 3g..3g+2)
    const int bb  = tid >> 3;           // batch within block
    const int b   = swz * BPB + bb;

    // q loads issued first (stream-once, 12.6 MB total)
    const float* rq = rev_q + (size_t)b * NJ + 3 * g;
    const float* pq = pri_q + (size_t)b * NJ + 3 * g;
    float qr[JPL] = {rq[0], rq[1], rq[2]};
    float qp[JPL] = {pq[0], pq[1], pq[2]};

    // ---- per-block statics (tiny, L2-hot after first blocks) ----
    if (tid < NJ) {
        const int j = tid;
        float R[9];
        rpy2R(rpy_off[j*3+0], rpy_off[j*3+1], rpy_off[j*3+2], R);
        s_stat[j*8+0] = make_float4(R[0], R[1], R[2], p_off[j*3+0]);
        s_stat[j*8+1] = make_float4(R[3], R[4], R[5], p_off[j*3+1]);
        s_stat[j*8+2] = make_float4(R[6], R[7], R[8], p_off[j*3+2]);

        float ax = rev_axis[j*3+0], ay = rev_axis[j*3+1], az = rev_axis[j*3+2];
        float n = sqrtf(ax*ax + ay*ay + az*az) + 1e-8f;   // ref: axis/(norm+EPS)
        ax /= n; ay /= n; az /= n;
        s_stat[j*8+3] = make_float4(ax, ay, az, ax*ax + ay*ay + az*az);
        s_stat[j*8+4] = make_float4(pri_axis[j*3+0], pri_axis[j*3+1], pri_axis[j*3+2], 0.f);

        rpy2R(rpy_trk[j*3+0], rpy_trk[j*3+1], rpy_trk[j*3+2], R);
        s_stat[j*8+5] = make_float4(R[0], R[1], R[2], p_trk[j*3+0]);
        s_stat[j*8+6] = make_float4(R[3], R[4], R[5], p_trk[j*3+1]);
        s_stat[j*8+7] = make_float4(R[6], R[7], R[8], p_trk[j*3+2]);
    }
    __syncthreads();

    // ---- local serial pass over this lane's 3 joints (from identity) ----
    float preR[JPL][9], prep[JPL][3];   // local pre' (pre-prefix JointSE3)
    float curR[9], curp[3];             // running local product -> lane product
    float tR[9], tp[3];                 // local post at this lane's tracked joint
    int jt = -1;

#pragma unroll
    for (int k = 0; k < JPL; k++) {
        const int j = 3 * g + k;
        const float4 s0 = s_stat[j*8+0], s1 = s_stat[j*8+1], s2 = s_stat[j*8+2];
        const float4 s3 = s_stat[j*8+3], s4 = s_stat[j*8+4];
        float ToR[9] = {s0.x,s0.y,s0.z, s1.x,s1.y,s1.z, s2.x,s2.y,s2.z};
        float Top[3] = {s0.w, s1.w, s2.w};

        if (k == 0) {
#pragma unroll
            for (int i = 0; i < 9; i++) preR[0][i] = ToR[i];
#pragma unroll
            for (int i = 0; i < 3; i++) prep[0][i] = Top[i];
        } else {
            compose(curR, curp, ToR, Top, preR[k], prep[k]);
        }

        // joint transform: Rodrigues + prismatic
        float s = __sinf(qr[k]), c = __cosf(qr[k]), c1 = 1.0f - c;
        const float ax = s3.x, ay = s3.y, az = s3.z, adot = s3.w;
        float jR[9];
        jR[0] = 1.f + c1*(ax*ax - adot);  jR[1] = -s*az + c1*ax*ay;        jR[2] =  s*ay + c1*ax*az;
        jR[3] =  s*az + c1*ax*ay;         jR[4] = 1.f + c1*(ay*ay - adot); jR[5] = -s*ax + c1*ay*az;
        jR[6] = -s*ay + c1*ax*az;         jR[7] =  s*ax + c1*ay*az;        jR[8] = 1.f + c1*(az*az - adot);
        float v0 = qp[k]*s4.x, v1 = qp[k]*s4.y, v2 = qp[k]*s4.z;
        float jp[3];
        jp[0] = jR[0]*v0 + jR[1]*v1 + jR[2]*v2;
        jp[1] = jR[3]*v0 + jR[4]*v1 + jR[5]*v2;
        jp[2] = jR[6]*v0 + jR[7]*v1 + jR[8]*v2;

        compose(preR[k], prep[k], jR, jp, curR, curp);   // cur = pre' o Tj

        if ((j & 3) == 3) {   // lane's tracked joint (at most one per lane)
            jt = j;
#pragma unroll
            for (int i = 0; i < 9; i++) tR[i] = curR[i];
#pragma unroll
            for (int i = 0; i < 3; i++) tp[i] = curp[i];
        }
    }

    // ---- 3-step inclusive scan of lane products over 8 lanes ----
#pragma unroll
    for (int sft = 1; sft < GRP; sft <<= 1) {
        float fR[9], fp[3];
#pragma unroll
        for (int i = 0; i < 9; i++) fR[i] = __shfl_up(curR[i], sft, GRP);
#pragma unroll
        for (int i = 0; i < 3; i++) fp[i] = __shfl_up(curp[i], sft, GRP);
        if (g >= sft) {
            float nR[9], np[3];
            compose(fR, fp, curR, curp, nR, np);   // earlier lanes on the left
#pragma unroll
            for (int i = 0; i < 9; i++) curR[i] = nR[i];
#pragma unroll
            for (int i = 0; i < 3; i++) curp[i] = np[i];
        }
    }

    // ---- exclusive prefix E (identity for lane 0) ----
    float ER[9], Ep[3];
#pragma unroll
    for (int i = 0; i < 9; i++) ER[i] = __shfl_up(curR[i], 1, GRP);
#pragma unroll
    for (int i = 0; i < 3; i++) Ep[i] = __shfl_up(curp[i], 1, GRP);
    if (g == 0) {
        ER[0]=1.f; ER[1]=0.f; ER[2]=0.f; ER[3]=0.f; ER[4]=1.f; ER[5]=0.f;
        ER[6]=0.f; ER[7]=0.f; ER[8]=1.f; Ep[0]=0.f; Ep[1]=0.f; Ep[2]=0.f;
    }

    // ---- tracked output: (E o post'_t) o T_track, stored direct ----
    if (jt >= 0) {
        float PR[9], Pp[3];
        compose(ER, Ep, tR, tp, PR, Pp);
        const float4 t0 = s_stat[jt*8+5], t1 = s_stat[jt*8+6], t2 = s_stat[jt*8+7];
        float TtR[9] = {t0.x,t0.y,t0.z, t1.x,t1.y,t1.z, t2.x,t2.y,t2.z};
        float Ttp[3] = {t0.w, t1.w, t2.w};
        float TR[9], Tp[3];
        compose(PR, Pp, TtR, Ttp, TR, Tp);
        float4* td = (float4*)out_track + ((size_t)b * NTRK + (jt >> 2)) * 4;
        td[0] = make_float4(TR[0], TR[1], TR[2], Tp[0]);
        td[1] = make_float4(TR[3], TR[4], TR[5], Tp[1]);
        td[2] = make_float4(TR[6], TR[7], TR[8], Tp[2]);
        td[3] = make_float4(0.f, 0.f, 0.f, 1.f);
    }

    // ---- finalize pre_j = E o pre'_k, stage 3 rows into LDS ----
#pragma unroll
    for (int k = 0; k < JPL; k++) {
        float FR[9], Fp[3];
        compose(ER, Ep, preR[k], prep[k], FR, Fp);
        f4* dst = &s_j[bb * PAD3 + (3 * g + k) * 3];
        dst[0] = (f4){FR[0], FR[1], FR[2], Fp[0]};
        dst[1] = (f4){FR[3], FR[4], FR[5], Fp[1]};
        dst[2] = (f4){FR[6], FR[7], FR[8], Fp[2]};
    }
    __syncthreads();

    // ---- coalesced nontemporal flush; constant bottom rows from immediates ----
    f4* oj = (f4*)out_joint + (size_t)swz * (BPB * NJ * 4);
#pragma unroll
    for (int it = 0; it < 12; it++) {
        int flat = it * 256 + tid;          // 0 .. 3071 output f4 index
        int bI = flat / 96;                 // batch within block (magic-mul)
        int rem = flat - bI * 96;
        int r = rem & 3;                    // row within 4x4
        int jj = rem >> 2;                  // joint
        f4 v;
        if (r == 3) v = (f4){0.f, 0.f, 0.f, 1.f};
        else        v = s_j[bI * PAD3 + jj * 3 + r];
        __builtin_nontemporal_store(v, &oj[flat]);
    }
}

extern "C" void kernel_launch(void* const* d_in, const int* in_sizes, int n_in,
                              void* d_out, int out_size, void* d_ws, size_t ws_size,
                              hipStream_t stream) {
    const float* rev_q    = (const float*)d_in[0];
    const float* pri_q    = (const float*)d_in[1];
    const float* p_off    = (const float*)d_in[2];
    const float* rpy_off  = (const float*)d_in[3];
    const float* rev_axis = (const float*)d_in[4];
    const float* pri_axis = (const float*)d_in[5];
    const float* p_trk    = (const float*)d_in[6];
    const float* rpy_trk  = (const float*)d_in[7];

    float* out = (float*)d_out;
    float* out_track = out;                           // (B, 6, 4, 4)
    float* out_joint = out + (size_t)NB * NTRK * 16;  // (B, 24, 4, 4)

    dim3 grid(NWG), block(256);
    hipLaunchKernelGGL(fk_kernel, grid, block, 0, stream,
                       rev_q, pri_q, p_off, rpy_off, rev_axis, pri_axis,
                       p_trk, rpy_trk, out_track, out_joint);
}